// Round 16
// baseline (1568.550 us; speedup 1.0000x reference)
//
#include <hip/hip_runtime.h>
#include <math.h>

// ---- problem constants ----
#define CH 56          // channels
#define NBD 8          // "B" depth dim
#define HH 192
#define WW 192
#define PLANE (HH*WW)          // 36864
#define S3 (NBD*PLANE)         // 294912 positions per channel
#define NWX 24                 // windows per row/col
#define NTOK 64                // tokens per window
#define DHALF 28               // q/k/v channels
#define DHEAD 14               // per-head dim
// LDS padded strides (bank-conflict avoidance)
#define XNP 57
#define QKP 29
// FFN MFMA halo: per-branch LDS bytes (100 pixels * 64 ch * 2B)
#define FFN_BR_OFF 12800

typedef __attribute__((ext_vector_type(8))) short short8;
typedef __attribute__((ext_vector_type(4))) float f32x4;

__device__ __forceinline__ int gidx(int c, int b, int y, int x) {
    return ((c * NBD + b) * HH + y) * WW + x;
}

__device__ __forceinline__ unsigned short f2bf(float f) {
    unsigned int u = __float_as_uint(f);
    u = (u + 0x7FFFu + ((u >> 16) & 1u)) >> 16;   // RNE
    return (unsigned short)u;
}

// =====================================================================
// Kernel 1: FA — fused PreNorm + windowed self-attention, per (window,b)
// Register-resident sim: thread (r=tid>>2, sub=tid&3) owns cols
// 16*sub..16*sub+15. Per-instruction k/v reads: 4 addrs, 2 banks, 2
// addrs/bank (2-way = free, m136). No s_sim -> LDS 36.9 KB, 4 blk/CU.
// =====================================================================
__global__ __launch_bounds__(256) void fa_kernel(
    const float* __restrict__ x,
    const float* __restrict__ lnw, const float* __restrict__ lnb,
    const float* __restrict__ qkw, const float* __restrict__ vw,
    const float* __restrict__ ow,  const float* __restrict__ ob,
    const float* __restrict__ pcqw, const float* __restrict__ pcqb,
    const float* __restrict__ pckw, const float* __restrict__ pckb,
    const float* __restrict__ m1,  const float* __restrict__ m2a,
    const float* __restrict__ m2b,
    float* __restrict__ x1)
{
    // pool: s_xn [64][57] (phases 1-3) -> s_o[64][29] + Sq/Sk/t/t2/theta
    __shared__ __align__(16) char s_pool[NTOK * XNP * 4];   // 14592 B
    __shared__ float s_q[NTOK * QKP];
    __shared__ float s_k[NTOK * QKP];
    __shared__ float s_v[NTOK * QKP];

    float* s_xn = (float*)s_pool;
    float* s_o  = (float*)s_pool;                  // [64][29] = 7424 B
    float* s_Sq = (float*)(s_pool + 7424);         // [2][64]
    float* s_Sk = (float*)(s_pool + 7936);         // [2][64]
    float* s_t  = (float*)(s_pool + 8448);         // [64]
    float* s_t2 = (float*)(s_pool + 8704);         // [64]
    float* s_th = (float*)(s_pool + 8960);         // [1]

    const int tid = threadIdx.x;
    const int b   = blockIdx.x & 7;
    const int win = blockIdx.x >> 3;
    const int y0  = (win / NWX) * 8;
    const int x0  = (win % NWX) * 8;

    // ---- load window (raw) ----
    for (int i = tid; i < NTOK * CH; i += 256) {
        int c = i >> 6, tok = i & 63;
        s_xn[tok * XNP + c] = x[gidx(c, b, y0 + (tok >> 3), x0 + (tok & 7))];
    }
    __syncthreads();

    // ---- LN in place: 4 lanes/token, one-pass stats ----
    {
        const int tok = tid >> 2, sub = tid & 3;
        float sm = 0.f, sq = 0.f;
        #pragma unroll
        for (int cc = 0; cc < 14; cc++) {
            float v = s_xn[tok * XNP + sub * 14 + cc];
            sm += v; sq += v * v;
        }
        sm += __shfl_xor(sm, 1); sm += __shfl_xor(sm, 2);
        sq += __shfl_xor(sq, 1); sq += __shfl_xor(sq, 2);
        float mu = sm * (1.f / CH);
        float rs = rsqrtf(sq * (1.f / CH) - mu * mu + 1e-5f);
        #pragma unroll
        for (int cc = 0; cc < 14; cc++) {
            int c = sub * 14 + cc;
            s_xn[tok * XNP + c] = (s_xn[tok * XNP + c] - mu) * rs * lnw[c] + lnb[c];
        }
    }
    __syncthreads();

    // ---- projections: 84 outputs x 64 tokens; weight rows wave-uniform ----
    for (int i = tid; i < NTOK * 84; i += 256) {
        int o = __builtin_amdgcn_readfirstlane(i >> 6);
        int tok = i & 63;
        const float* wr = (o < 56) ? (qkw + o * 56) : (vw + (o - 56) * 56);
        float acc = 0.f;
        #pragma unroll
        for (int c = 0; c < CH; c++) acc += s_xn[tok * XNP + c] * wr[c];
        if (o < 28)       s_q[tok * QKP + o]        = acc;
        else if (o < 56)  s_k[tok * QKP + (o - 28)] = acc;
        else              s_v[tok * QKP + (o - 56)] = acc;
    }
    __syncthreads();       // s_xn dead from here; pool becomes s_o/stats

    // ---- Sq/Sk for BOTH heads (4 groups of 64 threads) ----
    {
        int grpid = tid >> 6;
        int tok = tid & 63;
        int h = grpid & 1;
        if (grpid < 2) {
            float a = pcqb[0];
            #pragma unroll
            for (int d = 0; d < DHEAD; d++) a += s_q[tok * QKP + h * DHEAD + d] * pcqw[d];
            s_Sq[h * 64 + tok] = a;
        } else {
            float a = pckb[0];
            #pragma unroll
            for (int d = 0; d < DHEAD; d++) a += s_k[tok * QKP + h * DHEAD + d] * pckw[d];
            s_Sk[h * 64 + tok] = a;
        }
    }
    __syncthreads();

    const int r = tid >> 2, sub = tid & 3, j0 = sub * 16;

    // ---- heads ----
    for (int h = 0; h < 2; h++) {
        const int ho = h * DHEAD;
        // sim into 16 regs: outer d, inner jj (uniform jj,d per instr ->
        // k reads are 4 addrs on 2 banks = 2-way free; q reads broadcast)
        float vals[16];
        #pragma unroll
        for (int jj = 0; jj < 16; jj++) vals[jj] = 0.f;
        #pragma unroll
        for (int d = 0; d < DHEAD; d++) {
            float qd = s_q[r * QKP + ho + d];
            #pragma unroll
            for (int jj = 0; jj < 16; jj++)
                vals[jj] += qd * s_k[(j0 + jj) * QKP + ho + d];
        }
        // t[r] = sum_{j != r} sim[r][j]*m1[j] (raw sim, from regs)
        {
            float a = 0.f;
            #pragma unroll
            for (int jj = 0; jj < 16; jj++) {
                int j = j0 + jj;
                a += (j != r) ? vals[jj] * m1[j] : 0.f;
            }
            a += __shfl_xor(a, 1); a += __shfl_xor(a, 2);
            if (sub == 0) s_t[r] = a;
        }
        __syncthreads();
        // t2[r] = leaky_relu(sum_i t[i]*m2a[r][i]) — 4 lanes/row
        {
            float a = 0.f;
            #pragma unroll
            for (int jj = 0; jj < 16; jj++) {
                int i2 = j0 + jj;
                a += s_t[i2] * m2a[r * 64 + i2];
            }
            a += __shfl_xor(a, 1); a += __shfl_xor(a, 2);
            if (sub == 0) s_t2[r] = (a > 0.f) ? a : 0.1f * a;
        }
        __syncthreads();
        // theta = dot(t2, m2b) — wave reduce
        if (tid < 64) {
            float a = s_t2[tid] * m2b[tid];
            #pragma unroll
            for (int off = 1; off < 64; off <<= 1) a += __shfl_xor(a, off);
            if (tid == 0) s_th[0] = a;
        }
        __syncthreads();
        // Sigma scale + softmax + mask (in regs, same assoc as R15)
        {
            const float Sqi = s_Sq[h * 64 + r];
            const float th = s_th[0];
            float m = -1e30f;
            #pragma unroll
            for (int jj = 0; jj < 16; jj++) {
                float s = vals[jj] * Sqi * s_Sk[h * 64 + j0 + jj];
                vals[jj] = s;
                m = fmaxf(m, s);
            }
            m = fmaxf(m, __shfl_xor(m, 1));
            m = fmaxf(m, __shfl_xor(m, 2));
            float sum = 0.f;
            #pragma unroll
            for (int jj = 0; jj < 16; jj++) {
                float e = expf(vals[jj] - m);
                sum += e;
                vals[jj] = (vals[jj] > th) ? e : 0.f;
            }
            sum += __shfl_xor(sum, 1); sum += __shfl_xor(sum, 2);
            const float inv = 1.f / sum;
            #pragma unroll
            for (int jj = 0; jj < 16; jj++) vals[jj] *= inv;
        }
        // PV from regs: quarter-sums + 2-lane shfl (R12-verified pattern)
        #pragma unroll
        for (int d = 0; d < DHEAD; d++) {
            float a = 0.f;
            #pragma unroll
            for (int jj = 0; jj < 16; jj++)
                a += vals[jj] * s_v[(j0 + jj) * QKP + ho + d];
            a += __shfl_xor(a, 1);
            a += __shfl_xor(a, 2);
            if ((d & 3) == sub) s_o[r * QKP + ho + d] = a;
        }
        // no barrier: next head's phases touch only regs until the t-write,
        // and s_o columns are disjoint between heads
    }
    __syncthreads();

    // ---- epilogue: out-proj + bias + residual ----
    for (int i = tid; i < NTOK * CH; i += 256) {
        int c = __builtin_amdgcn_readfirstlane(i >> 6);
        int tok = i & 63;
        float a = ob[c];
        #pragma unroll
        for (int o = 0; o < DHALF; o++) a += s_o[tok * QKP + o] * ow[c * DHALF + o];
        int g = gidx(c, b, y0 + (tok >> 3), x0 + (tok & 7));
        x1[g] = a + x[g];
    }
}

// =====================================================================
// Kernel 2: LayerNorm over channel dim, fp32 out (for SCA convs)
// =====================================================================
__global__ __launch_bounds__(256) void ln_kernel(
    const float* __restrict__ in, const float* __restrict__ w,
    const float* __restrict__ b, float* __restrict__ outp)
{
    int p = blockIdx.x * 256 + threadIdx.x;
    if (p >= S3) return;
    float v[CH];
    float mu = 0.f;
    #pragma unroll
    for (int c = 0; c < CH; c++) { v[c] = in[(size_t)c * S3 + p]; mu += v[c]; }
    mu *= (1.f / CH);
    float var = 0.f;
    #pragma unroll
    for (int c = 0; c < CH; c++) { float d = v[c] - mu; var += d * d; }
    float rs = rsqrtf(var * (1.f / CH) + 1e-5f);
    #pragma unroll
    for (int c = 0; c < CH; c++)
        outp[(size_t)c * S3 + p] = (v[c] - mu) * rs * w[c] + b[c];
}

// =====================================================================
// Kernel 2b: LayerNorm -> bf16, channel-innermost [p][56] (for FFN MFMA)
// =====================================================================
__global__ __launch_bounds__(256) void ln_bf16_kernel(
    const float* __restrict__ in, const float* __restrict__ w,
    const float* __restrict__ b, unsigned short* __restrict__ outp)
{
    int p = blockIdx.x * 256 + threadIdx.x;
    if (p >= S3) return;
    float v[CH];
    float mu = 0.f;
    #pragma unroll
    for (int c = 0; c < CH; c++) { v[c] = in[(size_t)c * S3 + p]; mu += v[c]; }
    mu *= (1.f / CH);
    float var = 0.f;
    #pragma unroll
    for (int c = 0; c < CH; c++) { float d = v[c] - mu; var += d * d; }
    float rs = rsqrtf(var * (1.f / CH) + 1e-5f);
    unsigned int q[28];
    #pragma unroll
    for (int c = 0; c < CH; c += 2) {
        float a0 = (v[c]     - mu) * rs * w[c]     + b[c];
        float a1 = (v[c + 1] - mu) * rs * w[c + 1] + b[c + 1];
        q[c >> 1] = (unsigned int)f2bf(a0) | ((unsigned int)f2bf(a1) << 16);
    }
    uint4* dst = (uint4*)(outp + (size_t)p * 56);
    #pragma unroll
    for (int k = 0; k < 7; k++) {
        uint4 t; t.x = q[k*4]; t.y = q[k*4+1]; t.z = q[k*4+2]; t.w = q[k*4+3];
        dst[k] = t;
    }
}

// =====================================================================
// Kernel 3: grouped 3x3x3 conv, 4-wide in x (float4 core, guarded edges)
// =====================================================================
__global__ __launch_bounds__(256) void conv3_kernel(
    const float* __restrict__ in, const float* __restrict__ w,
    float* __restrict__ outp)
{
    int n = blockIdx.x * 256 + threadIdx.x;        // groups of 4 outputs
    if (n >= DHALF * S3 / 4) return;
    int o = n / (S3 / 4);
    int r = n - o * (S3 / 4);
    int z = r / (PLANE / 4);
    int t = r - z * (PLANE / 4);
    int y = t / (WW / 4);
    int xb = (t - y * (WW / 4)) * 4;
    float a0 = 0.f, a1 = 0.f, a2 = 0.f, a3 = 0.f;
    #pragma unroll
    for (int ic = 0; ic < 2; ic++) {
        const float* ip = in + (size_t)(2 * o + ic) * S3;
        const float* wp = w + (o * 2 + ic) * 27;
        #pragma unroll
        for (int dz = 0; dz < 3; dz++) {
            int zz = z + dz - 1;
            if (zz < 0 || zz >= NBD) continue;
            #pragma unroll
            for (int dy = 0; dy < 3; dy++) {
                int yy = y + dy - 1;
                if (yy < 0 || yy >= HH) continue;
                const float* row = ip + zz * PLANE + yy * WW + xb;
                float4 c4 = *(const float4*)row;
                float vm = (xb > 0) ? row[-1] : 0.f;
                float vp = (xb + 4 < WW) ? row[4] : 0.f;
                float w0 = wp[dz * 9 + dy * 3 + 0];
                float w1 = wp[dz * 9 + dy * 3 + 1];
                float w2 = wp[dz * 9 + dy * 3 + 2];
                a0 += vm   * w0 + c4.x * w1 + c4.y * w2;
                a1 += c4.x * w0 + c4.y * w1 + c4.z * w2;
                a2 += c4.y * w0 + c4.z * w1 + c4.w * w2;
                a3 += c4.z * w0 + c4.w * w1 + vp   * w2;
            }
        }
    }
    float4 res; res.x = a0; res.y = a1; res.z = a2; res.w = a3;
    *(float4*)(outp + (size_t)o * S3 + z * PLANE + y * WW + xb) = res;
}

// =====================================================================
// Kernel 3b: dual grouped 3x3x3 conv — same input, two weight sets
// =====================================================================
__global__ __launch_bounds__(256) void conv3_dual_kernel(
    const float* __restrict__ in,
    const float* __restrict__ wk, const float* __restrict__ wv,
    float* __restrict__ outk, float* __restrict__ outv)
{
    int n = blockIdx.x * 256 + threadIdx.x;
    if (n >= DHALF * S3 / 4) return;
    int o = n / (S3 / 4);
    int r = n - o * (S3 / 4);
    int z = r / (PLANE / 4);
    int t = r - z * (PLANE / 4);
    int y = t / (WW / 4);
    int xb = (t - y * (WW / 4)) * 4;
    float k0 = 0.f, k1 = 0.f, k2 = 0.f, k3 = 0.f;
    float v0 = 0.f, v1 = 0.f, v2 = 0.f, v3 = 0.f;
    #pragma unroll
    for (int ic = 0; ic < 2; ic++) {
        const float* ip  = in + (size_t)(2 * o + ic) * S3;
        const float* wpk = wk + (o * 2 + ic) * 27;
        const float* wpv = wv + (o * 2 + ic) * 27;
        #pragma unroll
        for (int dz = 0; dz < 3; dz++) {
            int zz = z + dz - 1;
            if (zz < 0 || zz >= NBD) continue;
            #pragma unroll
            for (int dy = 0; dy < 3; dy++) {
                int yy = y + dy - 1;
                if (yy < 0 || yy >= HH) continue;
                const float* row = ip + zz * PLANE + yy * WW + xb;
                float4 c4 = *(const float4*)row;
                float vm = (xb > 0) ? row[-1] : 0.f;
                float vp = (xb + 4 < WW) ? row[4] : 0.f;
                int wi = dz * 9 + dy * 3;
                float wk0 = wpk[wi], wk1 = wpk[wi + 1], wk2 = wpk[wi + 2];
                float wv0 = wpv[wi], wv1 = wpv[wi + 1], wv2 = wpv[wi + 2];
                k0 += vm   * wk0 + c4.x * wk1 + c4.y * wk2;
                k1 += c4.x * wk0 + c4.y * wk1 + c4.z * wk2;
                k2 += c4.y * wk0 + c4.z * wk1 + c4.w * wk2;
                k3 += c4.z * wk0 + c4.w * wk1 + vp   * wk2;
                v0 += vm   * wv0 + c4.x * wv1 + c4.y * wv2;
                v1 += c4.x * wv0 + c4.y * wv1 + c4.z * wv2;
                v2 += c4.y * wv0 + c4.z * wv1 + c4.w * wv2;
                v3 += c4.z * wv0 + c4.w * wv1 + vp   * wv2;
            }
        }
    }
    size_t base = (size_t)o * S3 + z * PLANE + y * WW + xb;
    float4 rk; rk.x = k0; rk.y = k1; rk.z = k2; rk.w = k3;
    float4 rv; rv.x = v0; rv.y = v1; rv.z = v2; rv.w = v3;
    *(float4*)(outk + base) = rk;
    *(float4*)(outv + base) = rv;
}

// =====================================================================
// Kernel 4: SCA — windowed cross-attention (register-resident sim core)
// =====================================================================
__global__ __launch_bounds__(256) void sca_kernel(
    const float* __restrict__ qb, const float* __restrict__ kb,
    const float* __restrict__ vb, const float* __restrict__ x1,
    const float* __restrict__ ocw,
    const float* __restrict__ pcqw, const float* __restrict__ pcqb,
    const float* __restrict__ pckw, const float* __restrict__ pckb,
    const float* __restrict__ m1,  const float* __restrict__ m2a,
    const float* __restrict__ m2b,
    float* __restrict__ x2)
{
    __shared__ float s_q[NTOK * QKP];
    __shared__ float s_k[NTOK * QKP];
    __shared__ float s_v[NTOK * QKP];
    __shared__ float s_o[NTOK * QKP];
    __shared__ float s_Sq[2][NTOK], s_Sk[2][NTOK];
    __shared__ float s_t[NTOK], s_t2[NTOK];
    __shared__ float s_theta;

    const int tid = threadIdx.x;
    const int b   = blockIdx.x & 7;
    const int win = blockIdx.x >> 3;
    const int y0  = (win / NWX) * 8;
    const int x0  = (win % NWX) * 8;

    for (int i = tid; i < NTOK * DHALF; i += 256) {
        int o = i >> 6, tok = i & 63;
        int g = ((o * NBD + b) * HH + y0 + (tok >> 3)) * WW + x0 + (tok & 7);
        s_q[tok * QKP + o] = qb[g];
        s_k[tok * QKP + o] = kb[g];
        s_v[tok * QKP + o] = vb[g];
    }
    __syncthreads();

    // Sq/Sk for both heads
    {
        int grpid = tid >> 6;
        int tok = tid & 63;
        int h = grpid & 1;
        if (grpid < 2) {
            float a = pcqb[0];
            #pragma unroll
            for (int d = 0; d < DHEAD; d++) a += s_q[tok * QKP + h * DHEAD + d] * pcqw[d];
            s_Sq[h][tok] = a;
        } else {
            float a = pckb[0];
            #pragma unroll
            for (int d = 0; d < DHEAD; d++) a += s_k[tok * QKP + h * DHEAD + d] * pckw[d];
            s_Sk[h][tok] = a;
        }
    }
    __syncthreads();

    const int r = tid >> 2, sub = tid & 3, j0 = sub * 16;

    for (int h = 0; h < 2; h++) {
        const int ho = h * DHEAD;
        float vals[16];
        #pragma unroll
        for (int jj = 0; jj < 16; jj++) vals[jj] = 0.f;
        #pragma unroll
        for (int d = 0; d < DHEAD; d++) {
            float qd = s_q[r * QKP + ho + d];
            #pragma unroll
            for (int jj = 0; jj < 16; jj++)
                vals[jj] += qd * s_k[(j0 + jj) * QKP + ho + d];
        }
        {
            float a = 0.f;
            #pragma unroll
            for (int jj = 0; jj < 16; jj++) {
                int j = j0 + jj;
                a += (j != r) ? vals[jj] * m1[j] : 0.f;
            }
            a += __shfl_xor(a, 1); a += __shfl_xor(a, 2);
            if (sub == 0) s_t[r] = a;
        }
        __syncthreads();
        {
            float a = 0.f;
            #pragma unroll
            for (int jj = 0; jj < 16; jj++) {
                int i2 = j0 + jj;
                a += s_t[i2] * m2a[r * 64 + i2];
            }
            a += __shfl_xor(a, 1); a += __shfl_xor(a, 2);
            if (sub == 0) s_t2[r] = (a > 0.f) ? a : 0.1f * a;
        }
        __syncthreads();
        if (tid < 64) {
            float a = s_t2[tid] * m2b[tid];
            #pragma unroll
            for (int off = 1; off < 64; off <<= 1) a += __shfl_xor(a, off);
            if (tid == 0) s_theta = a;
        }
        __syncthreads();
        {
            const float Sqi = s_Sq[h][r];
            const float th = s_theta;
            float m = -1e30f;
            #pragma unroll
            for (int jj = 0; jj < 16; jj++) {
                float s = vals[jj] * Sqi * s_Sk[h][j0 + jj];
                vals[jj] = s;
                m = fmaxf(m, s);
            }
            m = fmaxf(m, __shfl_xor(m, 1));
            m = fmaxf(m, __shfl_xor(m, 2));
            float sum = 0.f;
            #pragma unroll
            for (int jj = 0; jj < 16; jj++) {
                float e = expf(vals[jj] - m);
                sum += e;
                vals[jj] = (vals[jj] > th) ? e : 0.f;
            }
            sum += __shfl_xor(sum, 1); sum += __shfl_xor(sum, 2);
            const float inv = 1.f / sum;
            #pragma unroll
            for (int jj = 0; jj < 16; jj++) vals[jj] *= inv;
        }
        #pragma unroll
        for (int d = 0; d < DHEAD; d++) {
            float a = 0.f;
            #pragma unroll
            for (int jj = 0; jj < 16; jj++)
                a += vals[jj] * s_v[(j0 + jj) * QKP + ho + d];
            a += __shfl_xor(a, 1);
            a += __shfl_xor(a, 2);
            if ((d & 3) == sub) s_o[r * QKP + ho + d] = a;
        }
    }
    __syncthreads();

    // epilogue: 1x1x1 expand conv + residual
    for (int i = tid; i < NTOK * CH; i += 256) {
        int c = i >> 6, tok = i & 63;
        int g = gidx(c, b, y0 + (tok >> 3), x0 + (tok & 7));
        x2[g] = s_o[tok * QKP + (c >> 1)] * ocw[c] + x1[g];
    }
}

// =====================================================================
// Kernel 5a: collapse FFN weights + emit pre-swizzled bf16 A-fragments.
// =====================================================================
__global__ __launch_bounds__(256) void ffn_wprep_frag_kernel(
    const float* __restrict__ w1x, const float* __restrict__ w2x,
    const float* __restrict__ w1l, const float* __restrict__ w2l,
    unsigned short* __restrict__ wfrag)
{
    int idx = blockIdx.x * 256 + threadIdx.x;     // (f, lane)
    if (idx >= 144 * 64) return;
    int f = idx >> 6, lane = idx & 63;
    int br = f / 72;
    int r  = f - br * 72;
    int tap = r >> 3;
    int m   = (r & 7) >> 1;
    int ks  = r & 1;
    const float* w1 = br ? w1l : w1x;
    const float* w2 = br ? w2l : w2x;
    int o  = m * 16 + (lane & 15);
    int c0 = ks * 32 + (lane >> 4) * 8;
    unsigned short vals[8];
    #pragma unroll
    for (int j = 0; j < 8; j++) {
        int c = c0 + j;
        float a = 0.f;
        if (o < 56 && c < 56) {
            #pragma unroll
            for (int jj = 0; jj < 4; jj++)
                a += w2[(o * 4 + jj) * 9 + tap] * w1[(o * 4 + jj) * 56 + c];
        }
        vals[j] = f2bf(a);
    }
    uint4 packed;
    packed.x = (unsigned int)vals[0] | ((unsigned int)vals[1] << 16);
    packed.y = (unsigned int)vals[2] | ((unsigned int)vals[3] << 16);
    packed.z = (unsigned int)vals[4] | ((unsigned int)vals[5] << 16);
    packed.w = (unsigned int)vals[6] | ((unsigned int)vals[7] << 16);
    *(uint4*)(wfrag + (size_t)idx * 8) = packed;
}

// =====================================================================
// Kernel 5b: FFN via MFMA — 9 shifted GEMMs on bf16 LN'd inputs.
// =====================================================================
__global__ __launch_bounds__(256) void ffn_mfma_kernel(
    const unsigned short* __restrict__ xnb,   // LN'd x2, bf16 [p][56]
    const unsigned short* __restrict__ lnb,   // LN'd last, bf16 [p][56]
    const unsigned short* __restrict__ wfrag, // A-fragments
    const float* __restrict__ x2,             // residual fp32 [c][p]
    float* __restrict__ outp)
{
    __shared__ unsigned short s_t[2 * 100 * 64];   // 25.6 KB

    const int tid = threadIdx.x;
    const int z  = blockIdx.x / 576;
    const int t  = blockIdx.x % 576;
    const int ty = t / 24, tx = t % 24;
    const int y0 = ty * 8, x0 = tx * 8;

    for (int i = tid; i < 1600; i += 256) {
        int br = i / 800;
        int r  = i - br * 800;
        int hp = r >> 3, ck = r & 7;
        int hy = hp / 10, hx = hp - hy * 10;
        int y = y0 + hy - 1, xx = x0 + hx - 1;
        uint4 v = {0u, 0u, 0u, 0u};
        if (ck < 7 && y >= 0 && y < HH && xx >= 0 && xx < WW) {
            const unsigned short* src = (br ? lnb : xnb) +
                (size_t)(z * PLANE + y * WW + xx) * 56 + ck * 8;
            v = *(const uint4*)src;
        }
        unsigned int byte = (unsigned int)(br * FFN_BR_OFF + hp * 128 + ((ck ^ (hp & 7)) << 4));
        *(uint4*)((char*)s_t + byte) = v;
    }
    __syncthreads();

    const int wid  = tid >> 6;
    const int lane = tid & 63;
    const int col  = lane & 15;
    const int grp  = lane >> 4;

    f32x4 accx[4], accl[4];
    #pragma unroll
    for (int n = 0; n < 4; n++) {
        accx[n] = (f32x4){0.f, 0.f, 0.f, 0.f};
        accl[n] = (f32x4){0.f, 0.f, 0.f, 0.f};
    }

    const short8* wf = (const short8*)wfrag;

    for (int tap = 0; tap < 9; tap++) {
        int dy = tap / 3, dx = tap - dy * 3;
        short8 ax0 = wf[(tap * 8 + wid * 2 + 0) * 64 + lane];
        short8 ax1 = wf[(tap * 8 + wid * 2 + 1) * 64 + lane];
        short8 al0 = wf[(72 + tap * 8 + wid * 2 + 0) * 64 + lane];
        short8 al1 = wf[(72 + tap * 8 + wid * 2 + 1) * 64 + lane];
        #pragma unroll
        for (int nt = 0; nt < 4; nt++) {
            int pix = nt * 16 + col;
            int py = pix >> 3, px = pix & 7;
            int hp = (py + dy) * 10 + (px + dx);
            unsigned int base = (unsigned int)(hp * 128);
            unsigned int sw = (unsigned int)(hp & 7);
            unsigned int o0 = base + ((grp ^ sw) << 4);
            short8 bx0 = *(const short8*)((const char*)s_t + o0);
            short8 bl0 = *(const short8*)((const char*)s_t + FFN_BR_OFF + o0);
            accx[nt] = __builtin_amdgcn_mfma_f32_16x16x32_bf16(ax0, bx0, accx[nt], 0, 0, 0);
            accl[nt] = __builtin_amdgcn_mfma_f32_16x16x32_bf16(al0, bl0, accl[nt], 0, 0, 0);
            unsigned int o1 = base + (((4u + grp) ^ sw) << 4);
            short8 bx1 = *(const short8*)((const char*)s_t + o1);
            short8 bl1 = *(const short8*)((const char*)s_t + FFN_BR_OFF + o1);
            accx[nt] = __builtin_amdgcn_mfma_f32_16x16x32_bf16(ax1, bx1, accx[nt], 0, 0, 0);
            accl[nt] = __builtin_amdgcn_mfma_f32_16x16x32_bf16(al1, bl1, accl[nt], 0, 0, 0);
        }
    }

    #pragma unroll
    for (int nt = 0; nt < 4; nt++) {
        int pix = nt * 16 + col;
        int py = pix >> 3, px = pix & 7;
        int p = z * PLANE + (y0 + py) * WW + (x0 + px);
        #pragma unroll
        for (int reg = 0; reg < 4; reg++) {
            int o = wid * 16 + grp * 4 + reg;
            if (o < 56) {
                float lv = accl[nt][reg];
                float ge = 0.5f * lv * (1.f + erff(lv * 0.70710678118654752f));
                size_t g = (size_t)o * S3 + p;
                outp[g] = accx[nt][reg] * ge + x2[g];
            }
        }
    }
}

// =====================================================================
extern "C" void kernel_launch(void* const* d_in, const int* in_sizes, int n_in,
                              void* d_out, int out_size, void* d_ws, size_t ws_size,
                              hipStream_t stream)
{
    (void)in_sizes; (void)n_in; (void)out_size; (void)ws_size;
    const float* x         = (const float*)d_in[0];
    const float* last      = (const float*)d_in[1];
    const float* fa_ln_w   = (const float*)d_in[2];
    const float* fa_ln_b   = (const float*)d_in[3];
    const float* fa_qk_w   = (const float*)d_in[4];
    const float* fa_v_w    = (const float*)d_in[5];
    const float* fa_out_w  = (const float*)d_in[6];
    const float* fa_out_b  = (const float*)d_in[7];
    const float* fa_pcq_w  = (const float*)d_in[8];
    const float* fa_pcq_b  = (const float*)d_in[9];
    const float* fa_pck_w  = (const float*)d_in[10];
    const float* fa_pck_b  = (const float*)d_in[11];
    const float* fa_m1_w   = (const float*)d_in[12];
    const float* fa_m2a_w  = (const float*)d_in[13];
    const float* fa_m2b_w  = (const float*)d_in[14];
    const float* sca_ln1_w = (const float*)d_in[15];
    const float* sca_ln1_b = (const float*)d_in[16];
    const float* sca_ln2_w = (const float*)d_in[17];
    const float* sca_ln2_b = (const float*)d_in[18];
    const float* sca_q_w   = (const float*)d_in[19];
    const float* sca_k_w   = (const float*)d_in[20];
    const float* sca_v_w   = (const float*)d_in[21];
    const float* sca_out_w = (const float*)d_in[22];
    const float* sca_pcq_w = (const float*)d_in[23];
    const float* sca_pcq_b = (const float*)d_in[24];
    const float* sca_pck_w = (const float*)d_in[25];
    const float* sca_pck_b = (const float*)d_in[26];
    const float* sca_m1_w  = (const float*)d_in[27];
    const float* sca_m2a_w = (const float*)d_in[28];
    const float* sca_m2b_w = (const float*)d_in[29];
    const float* ffn_ln1_w = (const float*)d_in[30];
    const float* ffn_ln1_b = (const float*)d_in[31];
    const float* ffn_ln2_w = (const float*)d_in[32];
    const float* ffn_ln2_b = (const float*)d_in[33];
    const float* ffn_x1_w  = (const float*)d_in[34];
    const float* ffn_x2_w  = (const float*)d_in[35];
    const float* ffn_l1_w  = (const float*)d_in[36];
    const float* ffn_l2_w  = (const float*)d_in[37];
    float* out = (float*)d_out;
    float* ws  = (float*)d_ws;

    const size_t FULL = (size_t)CH * S3;      // 16,515,072 floats
    const size_t HALF = (size_t)DHALF * S3;
    float* x1    = ws;                        // FA output (freed after sca)
    float* lnbuf = ws + FULL;                 // LN scratch -> x2
    float* qb    = lnbuf + FULL;
    float* kb    = qb + HALF;
    float* vb    = kb + HALF;
    unsigned short* wfrag = (unsigned short*)(vb + HALF);  // 147 KB
    float* x2    = lnbuf;
    unsigned short* xnb  = (unsigned short*)ws;        // bytes [0, 33MB)
    unsigned short* lnbb = (unsigned short*)ws + FULL; // bytes [33MB, 66MB)

    // --- FFN weight fragments (independent) ---
    ffn_wprep_frag_kernel<<<dim3(36), dim3(256), 0, stream>>>(
        ffn_x1_w, ffn_x2_w, ffn_l1_w, ffn_l2_w, wfrag);

    // --- FA ---
    fa_kernel<<<dim3(4608), dim3(256), 0, stream>>>(
        x, fa_ln_w, fa_ln_b, fa_qk_w, fa_v_w, fa_out_w, fa_out_b,
        fa_pcq_w, fa_pcq_b, fa_pck_w, fa_pck_b, fa_m1_w, fa_m2a_w, fa_m2b_w, x1);

    // --- SCA: LN + grouped convs (k+v merged; 4-wide) ---
    ln_kernel<<<dim3(S3 / 256), dim3(256), 0, stream>>>(x1, sca_ln1_w, sca_ln1_b, lnbuf);
    conv3_kernel<<<dim3(DHALF * S3 / 4 / 256), dim3(256), 0, stream>>>(lnbuf, sca_q_w, qb);
    ln_kernel<<<dim3(S3 / 256), dim3(256), 0, stream>>>(last, sca_ln2_w, sca_ln2_b, lnbuf);
    conv3_dual_kernel<<<dim3(DHALF * S3 / 4 / 256), dim3(256), 0, stream>>>(
        lnbuf, sca_k_w, sca_v_w, kb, vb);

    sca_kernel<<<dim3(4608), dim3(256), 0, stream>>>(
        qb, kb, vb, x1, sca_out_w,
        sca_pcq_w, sca_pcq_b, sca_pck_w, sca_pck_b, sca_m1_w, sca_m2a_w, sca_m2b_w, x2);

    // --- FFN: LN->bf16, then MFMA conv ---
    ln_bf16_kernel<<<dim3(S3 / 256), dim3(256), 0, stream>>>(x2,   ffn_ln1_w, ffn_ln1_b, xnb);
    ln_bf16_kernel<<<dim3(S3 / 256), dim3(256), 0, stream>>>(last, ffn_ln2_w, ffn_ln2_b, lnbb);
    ffn_mfma_kernel<<<dim3(4608), dim3(256), 0, stream>>>(xnb, lnbb, wfrag, x2, out);
}

// Round 17
// 969.179 us; speedup vs baseline: 1.6184x; 1.6184x over previous
//
#include <hip/hip_runtime.h>
#include <math.h>

// ---- problem constants ----
#define CH 56          // channels
#define NBD 8          // "B" depth dim
#define HH 192
#define WW 192
#define PLANE (HH*WW)          // 36864
#define S3 (NBD*PLANE)         // 294912 positions per channel
#define NWX 24                 // windows per row/col
#define NTOK 64                // tokens per window
#define DHALF 28               // q/k/v channels
#define DHEAD 14               // per-head dim
// LDS padded strides (bank-conflict avoidance)
#define XNP 57
#define QKP 29
#define SIMP 65
// FFN MFMA halo: per-branch LDS bytes (100 pixels * 64 ch * 2B)
#define FFN_BR_OFF 12800

typedef __attribute__((ext_vector_type(8))) short short8;
typedef __attribute__((ext_vector_type(4))) float f32x4;

__device__ __forceinline__ int gidx(int c, int b, int y, int x) {
    return ((c * NBD + b) * HH + y) * WW + x;
}

__device__ __forceinline__ unsigned short f2bf(float f) {
    unsigned int u = __float_as_uint(f);
    u = (u + 0x7FFFu + ((u >> 16) & 1u)) >> 16;   // RNE
    return (unsigned short)u;
}

// =====================================================================
// Kernel 1: FA — fused PreNorm + windowed self-attention, per (window,b)
// R15 structure (k-hoist sim via s_sim, 4-lane rows); softmax and PV
// fused: normalized attn stays in regs, PV consumes it directly.
// =====================================================================
__global__ __launch_bounds__(256) void fa_kernel(
    const float* __restrict__ x,
    const float* __restrict__ lnw, const float* __restrict__ lnb,
    const float* __restrict__ qkw, const float* __restrict__ vw,
    const float* __restrict__ ow,  const float* __restrict__ ob,
    const float* __restrict__ pcqw, const float* __restrict__ pcqb,
    const float* __restrict__ pckw, const float* __restrict__ pckb,
    const float* __restrict__ m1,  const float* __restrict__ m2a,
    const float* __restrict__ m2b,
    float* __restrict__ x1)
{
    // pool: s_xn [64][57] (phases 1-3) -> s_o[64][29] + Sq/Sk/t/t2/theta
    __shared__ __align__(16) char s_pool[NTOK * XNP * 4];   // 14592 B
    __shared__ float s_q[NTOK * QKP];
    __shared__ float s_k[NTOK * QKP];
    __shared__ float s_v[NTOK * QKP];
    __shared__ float s_sim[NTOK * SIMP];

    float* s_xn = (float*)s_pool;
    float* s_o  = (float*)s_pool;                  // [64][29] = 7424 B
    float* s_Sq = (float*)(s_pool + 7424);         // [2][64]
    float* s_Sk = (float*)(s_pool + 7936);         // [2][64]
    float* s_t  = (float*)(s_pool + 8448);         // [64]
    float* s_t2 = (float*)(s_pool + 8704);         // [64]
    float* s_th = (float*)(s_pool + 8960);         // [1]

    const int tid = threadIdx.x;
    const int b   = blockIdx.x & 7;
    const int win = blockIdx.x >> 3;
    const int y0  = (win / NWX) * 8;
    const int x0  = (win % NWX) * 8;

    // ---- load window (raw) ----
    for (int i = tid; i < NTOK * CH; i += 256) {
        int c = i >> 6, tok = i & 63;
        s_xn[tok * XNP + c] = x[gidx(c, b, y0 + (tok >> 3), x0 + (tok & 7))];
    }
    __syncthreads();

    // ---- LN in place: 4 lanes/token, one-pass stats ----
    {
        const int tok = tid >> 2, sub = tid & 3;
        float sm = 0.f, sq = 0.f;
        #pragma unroll
        for (int cc = 0; cc < 14; cc++) {
            float v = s_xn[tok * XNP + sub * 14 + cc];
            sm += v; sq += v * v;
        }
        sm += __shfl_xor(sm, 1); sm += __shfl_xor(sm, 2);
        sq += __shfl_xor(sq, 1); sq += __shfl_xor(sq, 2);
        float mu = sm * (1.f / CH);
        float rs = rsqrtf(sq * (1.f / CH) - mu * mu + 1e-5f);
        #pragma unroll
        for (int cc = 0; cc < 14; cc++) {
            int c = sub * 14 + cc;
            s_xn[tok * XNP + c] = (s_xn[tok * XNP + c] - mu) * rs * lnw[c] + lnb[c];
        }
    }
    __syncthreads();

    // ---- projections: 84 outputs x 64 tokens; weight rows wave-uniform ----
    for (int i = tid; i < NTOK * 84; i += 256) {
        int o = __builtin_amdgcn_readfirstlane(i >> 6);
        int tok = i & 63;
        const float* wr = (o < 56) ? (qkw + o * 56) : (vw + (o - 56) * 56);
        float acc = 0.f;
        #pragma unroll
        for (int c = 0; c < CH; c++) acc += s_xn[tok * XNP + c] * wr[c];
        if (o < 28)       s_q[tok * QKP + o]        = acc;
        else if (o < 56)  s_k[tok * QKP + (o - 28)] = acc;
        else              s_v[tok * QKP + (o - 56)] = acc;
    }
    __syncthreads();       // s_xn dead from here; pool becomes s_o/stats

    // ---- Sq/Sk for BOTH heads (4 groups of 64 threads) ----
    {
        int grpid = tid >> 6;
        int tok = tid & 63;
        int h = grpid & 1;
        if (grpid < 2) {
            float a = pcqb[0];
            #pragma unroll
            for (int d = 0; d < DHEAD; d++) a += s_q[tok * QKP + h * DHEAD + d] * pcqw[d];
            s_Sq[h * 64 + tok] = a;
        } else {
            float a = pckb[0];
            #pragma unroll
            for (int d = 0; d < DHEAD; d++) a += s_k[tok * QKP + h * DHEAD + d] * pckw[d];
            s_Sk[h * 64 + tok] = a;
        }
    }
    __syncthreads();

    // ---- heads ----
    for (int h = 0; h < 2; h++) {
        const int ho = h * DHEAD;
        // sim[i][j]: j = tid&63 fixed -> hoist k[j][.] into regs;
        // r = (tid>>6) + 4*it (wave-uniform -> broadcast q reads).
        {
            const int j   = tid & 63;
            const int r0w = tid >> 6;
            float kv[DHEAD];
            #pragma unroll
            for (int d = 0; d < DHEAD; d++) kv[d] = s_k[j * QKP + ho + d];
            #pragma unroll
            for (int it = 0; it < 16; it++) {
                int r = r0w + 4 * it;
                float a = 0.f;
                #pragma unroll
                for (int d = 0; d < DHEAD; d++)
                    a += s_q[r * QKP + ho + d] * kv[d];
                s_sim[r * SIMP + j] = a;
            }
        }
        __syncthreads();
        // t[r] = sum_{j != r} sim[r][j]*m1[j] — 4 lanes/row
        {
            const int r = tid >> 2, sub = tid & 3;
            float a = 0.f;
            #pragma unroll
            for (int jj = 0; jj < 16; jj++) {
                int j = sub * 16 + jj;
                a += (j != r) ? s_sim[r * SIMP + j] * m1[j] : 0.f;
            }
            a += __shfl_xor(a, 1); a += __shfl_xor(a, 2);
            if (sub == 0) s_t[r] = a;
        }
        __syncthreads();
        // t2[r] = leaky_relu(sum_i t[i]*m2a[r][i]) — 4 lanes/row
        {
            const int r = tid >> 2, sub = tid & 3;
            float a = 0.f;
            #pragma unroll
            for (int jj = 0; jj < 16; jj++) {
                int i2 = sub * 16 + jj;
                a += s_t[i2] * m2a[r * 64 + i2];
            }
            a += __shfl_xor(a, 1); a += __shfl_xor(a, 2);
            if (sub == 0) s_t2[r] = (a > 0.f) ? a : 0.1f * a;
        }
        __syncthreads();
        // theta = dot(t2, m2b) — wave reduce
        if (tid < 64) {
            float a = s_t2[tid] * m2b[tid];
            #pragma unroll
            for (int off = 1; off < 64; off <<= 1) a += __shfl_xor(a, off);
            if (tid == 0) s_th[0] = a;
        }
        __syncthreads();
        // sims scale + softmax + mask + PV — fused, attn stays in regs
        {
            const int r = tid >> 2, sub = tid & 3;
            const int j0 = sub * 16;
            const float Sqi = s_Sq[h * 64 + r];
            const float th = s_th[0];
            float vals[16];
            float m = -1e30f;
            #pragma unroll
            for (int jj = 0; jj < 16; jj++) {
                float s = s_sim[r * SIMP + j0 + jj] * Sqi * s_Sk[h * 64 + j0 + jj];
                vals[jj] = s;
                m = fmaxf(m, s);
            }
            m = fmaxf(m, __shfl_xor(m, 1));
            m = fmaxf(m, __shfl_xor(m, 2));
            float sum = 0.f;
            #pragma unroll
            for (int jj = 0; jj < 16; jj++) {
                float e = expf(vals[jj] - m);
                sum += e;
                vals[jj] = (vals[jj] > th) ? e : 0.f;
            }
            sum += __shfl_xor(sum, 1); sum += __shfl_xor(sum, 2);
            const float inv = 1.f / sum;
            #pragma unroll
            for (int jj = 0; jj < 16; jj++) vals[jj] *= inv;
            // PV: quarter-sums + 2-lane shfl (R12-verified)
            #pragma unroll 2
            for (int d = 0; d < DHEAD; d++) {
                float a = 0.f;
                #pragma unroll
                for (int jj = 0; jj < 16; jj++)
                    a += vals[jj] * s_v[(j0 + jj) * QKP + ho + d];
                a += __shfl_xor(a, 1);
                a += __shfl_xor(a, 2);
                if ((d & 3) == sub) s_o[r * QKP + ho + d] = a;
            }
        }
        __syncthreads();
    }

    // ---- epilogue: out-proj + bias + residual ----
    for (int i = tid; i < NTOK * CH; i += 256) {
        int c = __builtin_amdgcn_readfirstlane(i >> 6);
        int tok = i & 63;
        float a = ob[c];
        #pragma unroll
        for (int o = 0; o < DHALF; o++) a += s_o[tok * QKP + o] * ow[c * DHALF + o];
        int g = gidx(c, b, y0 + (tok >> 3), x0 + (tok & 7));
        x1[g] = a + x[g];
    }
}

// =====================================================================
// Kernel 2: LayerNorm over channel dim, fp32 out (for SCA convs)
// =====================================================================
__global__ __launch_bounds__(256) void ln_kernel(
    const float* __restrict__ in, const float* __restrict__ w,
    const float* __restrict__ b, float* __restrict__ outp)
{
    int p = blockIdx.x * 256 + threadIdx.x;
    if (p >= S3) return;
    float v[CH];
    float mu = 0.f;
    #pragma unroll
    for (int c = 0; c < CH; c++) { v[c] = in[(size_t)c * S3 + p]; mu += v[c]; }
    mu *= (1.f / CH);
    float var = 0.f;
    #pragma unroll
    for (int c = 0; c < CH; c++) { float d = v[c] - mu; var += d * d; }
    float rs = rsqrtf(var * (1.f / CH) + 1e-5f);
    #pragma unroll
    for (int c = 0; c < CH; c++)
        outp[(size_t)c * S3 + p] = (v[c] - mu) * rs * w[c] + b[c];
}

// =====================================================================
// Kernel 2b: LayerNorm -> bf16, channel-innermost [p][56] (for FFN MFMA)
// =====================================================================
__global__ __launch_bounds__(256) void ln_bf16_kernel(
    const float* __restrict__ in, const float* __restrict__ w,
    const float* __restrict__ b, unsigned short* __restrict__ outp)
{
    int p = blockIdx.x * 256 + threadIdx.x;
    if (p >= S3) return;
    float v[CH];
    float mu = 0.f;
    #pragma unroll
    for (int c = 0; c < CH; c++) { v[c] = in[(size_t)c * S3 + p]; mu += v[c]; }
    mu *= (1.f / CH);
    float var = 0.f;
    #pragma unroll
    for (int c = 0; c < CH; c++) { float d = v[c] - mu; var += d * d; }
    float rs = rsqrtf(var * (1.f / CH) + 1e-5f);
    unsigned int q[28];
    #pragma unroll
    for (int c = 0; c < CH; c += 2) {
        float a0 = (v[c]     - mu) * rs * w[c]     + b[c];
        float a1 = (v[c + 1] - mu) * rs * w[c + 1] + b[c + 1];
        q[c >> 1] = (unsigned int)f2bf(a0) | ((unsigned int)f2bf(a1) << 16);
    }
    uint4* dst = (uint4*)(outp + (size_t)p * 56);
    #pragma unroll
    for (int k = 0; k < 7; k++) {
        uint4 t; t.x = q[k*4]; t.y = q[k*4+1]; t.z = q[k*4+2]; t.w = q[k*4+3];
        dst[k] = t;
    }
}

// =====================================================================
// Kernel 3: grouped 3x3x3 conv, 4-wide in x (float4 core, guarded edges)
// =====================================================================
__global__ __launch_bounds__(256) void conv3_kernel(
    const float* __restrict__ in, const float* __restrict__ w,
    float* __restrict__ outp)
{
    int n = blockIdx.x * 256 + threadIdx.x;        // groups of 4 outputs
    if (n >= DHALF * S3 / 4) return;
    int o = n / (S3 / 4);
    int r = n - o * (S3 / 4);
    int z = r / (PLANE / 4);
    int t = r - z * (PLANE / 4);
    int y = t / (WW / 4);
    int xb = (t - y * (WW / 4)) * 4;
    float a0 = 0.f, a1 = 0.f, a2 = 0.f, a3 = 0.f;
    #pragma unroll
    for (int ic = 0; ic < 2; ic++) {
        const float* ip = in + (size_t)(2 * o + ic) * S3;
        const float* wp = w + (o * 2 + ic) * 27;
        #pragma unroll
        for (int dz = 0; dz < 3; dz++) {
            int zz = z + dz - 1;
            if (zz < 0 || zz >= NBD) continue;
            #pragma unroll
            for (int dy = 0; dy < 3; dy++) {
                int yy = y + dy - 1;
                if (yy < 0 || yy >= HH) continue;
                const float* row = ip + zz * PLANE + yy * WW + xb;
                float4 c4 = *(const float4*)row;
                float vm = (xb > 0) ? row[-1] : 0.f;
                float vp = (xb + 4 < WW) ? row[4] : 0.f;
                float w0 = wp[dz * 9 + dy * 3 + 0];
                float w1 = wp[dz * 9 + dy * 3 + 1];
                float w2 = wp[dz * 9 + dy * 3 + 2];
                a0 += vm   * w0 + c4.x * w1 + c4.y * w2;
                a1 += c4.x * w0 + c4.y * w1 + c4.z * w2;
                a2 += c4.y * w0 + c4.z * w1 + c4.w * w2;
                a3 += c4.z * w0 + c4.w * w1 + vp   * w2;
            }
        }
    }
    float4 res; res.x = a0; res.y = a1; res.z = a2; res.w = a3;
    *(float4*)(outp + (size_t)o * S3 + z * PLANE + y * WW + xb) = res;
}

// =====================================================================
// Kernel 3b: dual grouped 3x3x3 conv — same input, two weight sets
// =====================================================================
__global__ __launch_bounds__(256) void conv3_dual_kernel(
    const float* __restrict__ in,
    const float* __restrict__ wk, const float* __restrict__ wv,
    float* __restrict__ outk, float* __restrict__ outv)
{
    int n = blockIdx.x * 256 + threadIdx.x;
    if (n >= DHALF * S3 / 4) return;
    int o = n / (S3 / 4);
    int r = n - o * (S3 / 4);
    int z = r / (PLANE / 4);
    int t = r - z * (PLANE / 4);
    int y = t / (WW / 4);
    int xb = (t - y * (WW / 4)) * 4;
    float k0 = 0.f, k1 = 0.f, k2 = 0.f, k3 = 0.f;
    float v0 = 0.f, v1 = 0.f, v2 = 0.f, v3 = 0.f;
    #pragma unroll
    for (int ic = 0; ic < 2; ic++) {
        const float* ip  = in + (size_t)(2 * o + ic) * S3;
        const float* wpk = wk + (o * 2 + ic) * 27;
        const float* wpv = wv + (o * 2 + ic) * 27;
        #pragma unroll
        for (int dz = 0; dz < 3; dz++) {
            int zz = z + dz - 1;
            if (zz < 0 || zz >= NBD) continue;
            #pragma unroll
            for (int dy = 0; dy < 3; dy++) {
                int yy = y + dy - 1;
                if (yy < 0 || yy >= HH) continue;
                const float* row = ip + zz * PLANE + yy * WW + xb;
                float4 c4 = *(const float4*)row;
                float vm = (xb > 0) ? row[-1] : 0.f;
                float vp = (xb + 4 < WW) ? row[4] : 0.f;
                int wi = dz * 9 + dy * 3;
                float wk0 = wpk[wi], wk1 = wpk[wi + 1], wk2 = wpk[wi + 2];
                float wv0 = wpv[wi], wv1 = wpv[wi + 1], wv2 = wpv[wi + 2];
                k0 += vm   * wk0 + c4.x * wk1 + c4.y * wk2;
                k1 += c4.x * wk0 + c4.y * wk1 + c4.z * wk2;
                k2 += c4.y * wk0 + c4.z * wk1 + c4.w * wk2;
                k3 += c4.z * wk0 + c4.w * wk1 + vp   * wk2;
                v0 += vm   * wv0 + c4.x * wv1 + c4.y * wv2;
                v1 += c4.x * wv0 + c4.y * wv1 + c4.z * wv2;
                v2 += c4.y * wv0 + c4.z * wv1 + c4.w * wv2;
                v3 += c4.z * wv0 + c4.w * wv1 + vp   * wv2;
            }
        }
    }
    size_t base = (size_t)o * S3 + z * PLANE + y * WW + xb;
    float4 rk; rk.x = k0; rk.y = k1; rk.z = k2; rk.w = k3;
    float4 rv; rv.x = v0; rv.y = v1; rv.z = v2; rv.w = v3;
    *(float4*)(outk + base) = rk;
    *(float4*)(outv + base) = rv;
}

// =====================================================================
// Kernel 4: SCA — windowed cross-attention (R15 + fused softmax->PV)
// =====================================================================
__global__ __launch_bounds__(256) void sca_kernel(
    const float* __restrict__ qb, const float* __restrict__ kb,
    const float* __restrict__ vb, const float* __restrict__ x1,
    const float* __restrict__ ocw,
    const float* __restrict__ pcqw, const float* __restrict__ pcqb,
    const float* __restrict__ pckw, const float* __restrict__ pckb,
    const float* __restrict__ m1,  const float* __restrict__ m2a,
    const float* __restrict__ m2b,
    float* __restrict__ x2)
{
    __shared__ float s_q[NTOK * QKP];
    __shared__ float s_k[NTOK * QKP];
    __shared__ float s_v[NTOK * QKP];
    __shared__ float s_sim[NTOK * SIMP];
    __shared__ float s_o[NTOK * QKP];
    __shared__ float s_Sq[2][NTOK], s_Sk[2][NTOK];
    __shared__ float s_t[NTOK], s_t2[NTOK];
    __shared__ float s_theta;

    const int tid = threadIdx.x;
    const int b   = blockIdx.x & 7;
    const int win = blockIdx.x >> 3;
    const int y0  = (win / NWX) * 8;
    const int x0  = (win % NWX) * 8;

    for (int i = tid; i < NTOK * DHALF; i += 256) {
        int o = i >> 6, tok = i & 63;
        int g = ((o * NBD + b) * HH + y0 + (tok >> 3)) * WW + x0 + (tok & 7);
        s_q[tok * QKP + o] = qb[g];
        s_k[tok * QKP + o] = kb[g];
        s_v[tok * QKP + o] = vb[g];
    }
    __syncthreads();

    // Sq/Sk for both heads
    {
        int grpid = tid >> 6;
        int tok = tid & 63;
        int h = grpid & 1;
        if (grpid < 2) {
            float a = pcqb[0];
            #pragma unroll
            for (int d = 0; d < DHEAD; d++) a += s_q[tok * QKP + h * DHEAD + d] * pcqw[d];
            s_Sq[h][tok] = a;
        } else {
            float a = pckb[0];
            #pragma unroll
            for (int d = 0; d < DHEAD; d++) a += s_k[tok * QKP + h * DHEAD + d] * pckw[d];
            s_Sk[h][tok] = a;
        }
    }
    __syncthreads();

    for (int h = 0; h < 2; h++) {
        const int ho = h * DHEAD;
        // sim with k-reg hoist (j fixed per thread)
        {
            const int j   = tid & 63;
            const int r0w = tid >> 6;
            float kv[DHEAD];
            #pragma unroll
            for (int d = 0; d < DHEAD; d++) kv[d] = s_k[j * QKP + ho + d];
            #pragma unroll
            for (int it = 0; it < 16; it++) {
                int r = r0w + 4 * it;
                float a = 0.f;
                #pragma unroll
                for (int d = 0; d < DHEAD; d++)
                    a += s_q[r * QKP + ho + d] * kv[d];
                s_sim[r * SIMP + j] = a;
            }
        }
        __syncthreads();
        {
            const int r = tid >> 2, sub = tid & 3;
            float a = 0.f;
            #pragma unroll
            for (int jj = 0; jj < 16; jj++) {
                int j = sub * 16 + jj;
                a += (j != r) ? s_sim[r * SIMP + j] * m1[j] : 0.f;
            }
            a += __shfl_xor(a, 1); a += __shfl_xor(a, 2);
            if (sub == 0) s_t[r] = a;
        }
        __syncthreads();
        {
            const int r = tid >> 2, sub = tid & 3;
            float a = 0.f;
            #pragma unroll
            for (int jj = 0; jj < 16; jj++) {
                int i2 = sub * 16 + jj;
                a += s_t[i2] * m2a[r * 64 + i2];
            }
            a += __shfl_xor(a, 1); a += __shfl_xor(a, 2);
            if (sub == 0) s_t2[r] = (a > 0.f) ? a : 0.1f * a;
        }
        __syncthreads();
        if (tid < 64) {
            float a = s_t2[tid] * m2b[tid];
            #pragma unroll
            for (int off = 1; off < 64; off <<= 1) a += __shfl_xor(a, off);
            if (tid == 0) s_theta = a;
        }
        __syncthreads();
        // fused softmax + PV
        {
            const int r = tid >> 2, sub = tid & 3;
            const int j0 = sub * 16;
            const float Sqi = s_Sq[h][r];
            const float th = s_theta;
            float vals[16];
            float m = -1e30f;
            #pragma unroll
            for (int jj = 0; jj < 16; jj++) {
                float s = s_sim[r * SIMP + j0 + jj] * Sqi * s_Sk[h][j0 + jj];
                vals[jj] = s;
                m = fmaxf(m, s);
            }
            m = fmaxf(m, __shfl_xor(m, 1));
            m = fmaxf(m, __shfl_xor(m, 2));
            float sum = 0.f;
            #pragma unroll
            for (int jj = 0; jj < 16; jj++) {
                float e = expf(vals[jj] - m);
                sum += e;
                vals[jj] = (vals[jj] > th) ? e : 0.f;
            }
            sum += __shfl_xor(sum, 1); sum += __shfl_xor(sum, 2);
            const float inv = 1.f / sum;
            #pragma unroll
            for (int jj = 0; jj < 16; jj++) vals[jj] *= inv;
            #pragma unroll 2
            for (int d = 0; d < DHEAD; d++) {
                float a = 0.f;
                #pragma unroll
                for (int jj = 0; jj < 16; jj++)
                    a += vals[jj] * s_v[(j0 + jj) * QKP + ho + d];
                a += __shfl_xor(a, 1);
                a += __shfl_xor(a, 2);
                if ((d & 3) == sub) s_o[r * QKP + ho + d] = a;
            }
        }
        __syncthreads();
    }

    // epilogue: 1x1x1 expand conv + residual
    for (int i = tid; i < NTOK * CH; i += 256) {
        int c = i >> 6, tok = i & 63;
        int g = gidx(c, b, y0 + (tok >> 3), x0 + (tok & 7));
        x2[g] = s_o[tok * QKP + (c >> 1)] * ocw[c] + x1[g];
    }
}

// =====================================================================
// Kernel 5a: collapse FFN weights + emit pre-swizzled bf16 A-fragments.
// =====================================================================
__global__ __launch_bounds__(256) void ffn_wprep_frag_kernel(
    const float* __restrict__ w1x, const float* __restrict__ w2x,
    const float* __restrict__ w1l, const float* __restrict__ w2l,
    unsigned short* __restrict__ wfrag)
{
    int idx = blockIdx.x * 256 + threadIdx.x;     // (f, lane)
    if (idx >= 144 * 64) return;
    int f = idx >> 6, lane = idx & 63;
    int br = f / 72;
    int r  = f - br * 72;
    int tap = r >> 3;
    int m   = (r & 7) >> 1;
    int ks  = r & 1;
    const float* w1 = br ? w1l : w1x;
    const float* w2 = br ? w2l : w2x;
    int o  = m * 16 + (lane & 15);
    int c0 = ks * 32 + (lane >> 4) * 8;
    unsigned short vals[8];
    #pragma unroll
    for (int j = 0; j < 8; j++) {
        int c = c0 + j;
        float a = 0.f;
        if (o < 56 && c < 56) {
            #pragma unroll
            for (int jj = 0; jj < 4; jj++)
                a += w2[(o * 4 + jj) * 9 + tap] * w1[(o * 4 + jj) * 56 + c];
        }
        vals[j] = f2bf(a);
    }
    uint4 packed;
    packed.x = (unsigned int)vals[0] | ((unsigned int)vals[1] << 16);
    packed.y = (unsigned int)vals[2] | ((unsigned int)vals[3] << 16);
    packed.z = (unsigned int)vals[4] | ((unsigned int)vals[5] << 16);
    packed.w = (unsigned int)vals[6] | ((unsigned int)vals[7] << 16);
    *(uint4*)(wfrag + (size_t)idx * 8) = packed;
}

// =====================================================================
// Kernel 5b: FFN via MFMA — 9 shifted GEMMs on bf16 LN'd inputs.
// =====================================================================
__global__ __launch_bounds__(256) void ffn_mfma_kernel(
    const unsigned short* __restrict__ xnb,   // LN'd x2, bf16 [p][56]
    const unsigned short* __restrict__ lnb,   // LN'd last, bf16 [p][56]
    const unsigned short* __restrict__ wfrag, // A-fragments
    const float* __restrict__ x2,             // residual fp32 [c][p]
    float* __restrict__ outp)
{
    __shared__ unsigned short s_t[2 * 100 * 64];   // 25.6 KB

    const int tid = threadIdx.x;
    const int z  = blockIdx.x / 576;
    const int t  = blockIdx.x % 576;
    const int ty = t / 24, tx = t % 24;
    const int y0 = ty * 8, x0 = tx * 8;

    for (int i = tid; i < 1600; i += 256) {
        int br = i / 800;
        int r  = i - br * 800;
        int hp = r >> 3, ck = r & 7;
        int hy = hp / 10, hx = hp - hy * 10;
        int y = y0 + hy - 1, xx = x0 + hx - 1;
        uint4 v = {0u, 0u, 0u, 0u};
        if (ck < 7 && y >= 0 && y < HH && xx >= 0 && xx < WW) {
            const unsigned short* src = (br ? lnb : xnb) +
                (size_t)(z * PLANE + y * WW + xx) * 56 + ck * 8;
            v = *(const uint4*)src;
        }
        unsigned int byte = (unsigned int)(br * FFN_BR_OFF + hp * 128 + ((ck ^ (hp & 7)) << 4));
        *(uint4*)((char*)s_t + byte) = v;
    }
    __syncthreads();

    const int wid  = tid >> 6;
    const int lane = tid & 63;
    const int col  = lane & 15;
    const int grp  = lane >> 4;

    f32x4 accx[4], accl[4];
    #pragma unroll
    for (int n = 0; n < 4; n++) {
        accx[n] = (f32x4){0.f, 0.f, 0.f, 0.f};
        accl[n] = (f32x4){0.f, 0.f, 0.f, 0.f};
    }

    const short8* wf = (const short8*)wfrag;

    for (int tap = 0; tap < 9; tap++) {
        int dy = tap / 3, dx = tap - dy * 3;
        short8 ax0 = wf[(tap * 8 + wid * 2 + 0) * 64 + lane];
        short8 ax1 = wf[(tap * 8 + wid * 2 + 1) * 64 + lane];
        short8 al0 = wf[(72 + tap * 8 + wid * 2 + 0) * 64 + lane];
        short8 al1 = wf[(72 + tap * 8 + wid * 2 + 1) * 64 + lane];
        #pragma unroll
        for (int nt = 0; nt < 4; nt++) {
            int pix = nt * 16 + col;
            int py = pix >> 3, px = pix & 7;
            int hp = (py + dy) * 10 + (px + dx);
            unsigned int base = (unsigned int)(hp * 128);
            unsigned int sw = (unsigned int)(hp & 7);
            unsigned int o0 = base + ((grp ^ sw) << 4);
            short8 bx0 = *(const short8*)((const char*)s_t + o0);
            short8 bl0 = *(const short8*)((const char*)s_t + FFN_BR_OFF + o0);
            accx[nt] = __builtin_amdgcn_mfma_f32_16x16x32_bf16(ax0, bx0, accx[nt], 0, 0, 0);
            accl[nt] = __builtin_amdgcn_mfma_f32_16x16x32_bf16(al0, bl0, accl[nt], 0, 0, 0);
            unsigned int o1 = base + (((4u + grp) ^ sw) << 4);
            short8 bx1 = *(const short8*)((const char*)s_t + o1);
            short8 bl1 = *(const short8*)((const char*)s_t + FFN_BR_OFF + o1);
            accx[nt] = __builtin_amdgcn_mfma_f32_16x16x32_bf16(ax1, bx1, accx[nt], 0, 0, 0);
            accl[nt] = __builtin_amdgcn_mfma_f32_16x16x32_bf16(al1, bl1, accl[nt], 0, 0, 0);
        }
    }

    #pragma unroll
    for (int nt = 0; nt < 4; nt++) {
        int pix = nt * 16 + col;
        int py = pix >> 3, px = pix & 7;
        int p = z * PLANE + (y0 + py) * WW + (x0 + px);
        #pragma unroll
        for (int reg = 0; reg < 4; reg++) {
            int o = wid * 16 + grp * 4 + reg;
            if (o < 56) {
                float lv = accl[nt][reg];
                float ge = 0.5f * lv * (1.f + erff(lv * 0.70710678118654752f));
                size_t g = (size_t)o * S3 + p;
                outp[g] = accx[nt][reg] * ge + x2[g];
            }
        }
    }
}

// =====================================================================
extern "C" void kernel_launch(void* const* d_in, const int* in_sizes, int n_in,
                              void* d_out, int out_size, void* d_ws, size_t ws_size,
                              hipStream_t stream)
{
    (void)in_sizes; (void)n_in; (void)out_size; (void)ws_size;
    const float* x         = (const float*)d_in[0];
    const float* last      = (const float*)d_in[1];
    const float* fa_ln_w   = (const float*)d_in[2];
    const float* fa_ln_b   = (const float*)d_in[3];
    const float* fa_qk_w   = (const float*)d_in[4];
    const float* fa_v_w    = (const float*)d_in[5];
    const float* fa_out_w  = (const float*)d_in[6];
    const float* fa_out_b  = (const float*)d_in[7];
    const float* fa_pcq_w  = (const float*)d_in[8];
    const float* fa_pcq_b  = (const float*)d_in[9];
    const float* fa_pck_w  = (const float*)d_in[10];
    const float* fa_pck_b  = (const float*)d_in[11];
    const float* fa_m1_w   = (const float*)d_in[12];
    const float* fa_m2a_w  = (const float*)d_in[13];
    const float* fa_m2b_w  = (const float*)d_in[14];
    const float* sca_ln1_w = (const float*)d_in[15];
    const float* sca_ln1_b = (const float*)d_in[16];
    const float* sca_ln2_w = (const float*)d_in[17];
    const float* sca_ln2_b = (const float*)d_in[18];
    const float* sca_q_w   = (const float*)d_in[19];
    const float* sca_k_w   = (const float*)d_in[20];
    const float* sca_v_w   = (const float*)d_in[21];
    const float* sca_out_w = (const float*)d_in[22];
    const float* sca_pcq_w = (const float*)d_in[23];
    const float* sca_pcq_b = (const float*)d_in[24];
    const float* sca_pck_w = (const float*)d_in[25];
    const float* sca_pck_b = (const float*)d_in[26];
    const float* sca_m1_w  = (const float*)d_in[27];
    const float* sca_m2a_w = (const float*)d_in[28];
    const float* sca_m2b_w = (const float*)d_in[29];
    const float* ffn_ln1_w = (const float*)d_in[30];
    const float* ffn_ln1_b = (const float*)d_in[31];
    const float* ffn_ln2_w = (const float*)d_in[32];
    const float* ffn_ln2_b = (const float*)d_in[33];
    const float* ffn_x1_w  = (const float*)d_in[34];
    const float* ffn_x2_w  = (const float*)d_in[35];
    const float* ffn_l1_w  = (const float*)d_in[36];
    const float* ffn_l2_w  = (const float*)d_in[37];
    float* out = (float*)d_out;
    float* ws  = (float*)d_ws;

    const size_t FULL = (size_t)CH * S3;      // 16,515,072 floats
    const size_t HALF = (size_t)DHALF * S3;
    float* x1    = ws;                        // FA output (freed after sca)
    float* lnbuf = ws + FULL;                 // LN scratch -> x2
    float* qb    = lnbuf + FULL;
    float* kb    = qb + HALF;
    float* vb    = kb + HALF;
    unsigned short* wfrag = (unsigned short*)(vb + HALF);  // 147 KB
    float* x2    = lnbuf;
    unsigned short* xnb  = (unsigned short*)ws;        // bytes [0, 33MB)
    unsigned short* lnbb = (unsigned short*)ws + FULL; // bytes [33MB, 66MB)

    // --- FFN weight fragments (independent) ---
    ffn_wprep_frag_kernel<<<dim3(36), dim3(256), 0, stream>>>(
        ffn_x1_w, ffn_x2_w, ffn_l1_w, ffn_l2_w, wfrag);

    // --- FA ---
    fa_kernel<<<dim3(4608), dim3(256), 0, stream>>>(
        x, fa_ln_w, fa_ln_b, fa_qk_w, fa_v_w, fa_out_w, fa_out_b,
        fa_pcq_w, fa_pcq_b, fa_pck_w, fa_pck_b, fa_m1_w, fa_m2a_w, fa_m2b_w, x1);

    // --- SCA: LN + grouped convs (k+v merged; 4-wide) ---
    ln_kernel<<<dim3(S3 / 256), dim3(256), 0, stream>>>(x1, sca_ln1_w, sca_ln1_b, lnbuf);
    conv3_kernel<<<dim3(DHALF * S3 / 4 / 256), dim3(256), 0, stream>>>(lnbuf, sca_q_w, qb);
    ln_kernel<<<dim3(S3 / 256), dim3(256), 0, stream>>>(last, sca_ln2_w, sca_ln2_b, lnbuf);
    conv3_dual_kernel<<<dim3(DHALF * S3 / 4 / 256), dim3(256), 0, stream>>>(
        lnbuf, sca_k_w, sca_v_w, kb, vb);

    sca_kernel<<<dim3(4608), dim3(256), 0, stream>>>(
        qb, kb, vb, x1, sca_out_w,
        sca_pcq_w, sca_pcq_b, sca_pck_w, sca_pck_b, sca_m1_w, sca_m2a_w, sca_m2b_w, x2);

    // --- FFN: LN->bf16, then MFMA conv ---
    ln_bf16_kernel<<<dim3(S3 / 256), dim3(256), 0, stream>>>(x2,   ffn_ln1_w, ffn_ln1_b, xnb);
    ln_bf16_kernel<<<dim3(S3 / 256), dim3(256), 0, stream>>>(last, ffn_ln2_w, ffn_ln2_b, lnbb);
    ffn_mfma_kernel<<<dim3(4608), dim3(256), 0, stream>>>(xnb, lnbb, wfrag, x2, out);
}